// Round 1
// baseline (10432.034 us; speedup 1.0000x reference)
//
#include <hip/hip_runtime.h>

// Problem dims (fixed)
constexpr int Bb = 32;    // batch
constexpr int Tt = 1024;  // time steps
constexpr int Hh = 1024;  // hidden
constexpr int Di = 512;   // input dim
constexpr int Do = 512;   // output dim

using bf16x8 = __attribute__((ext_vector_type(8))) short;
using f32x4  = __attribute__((ext_vector_type(4))) float;

__device__ __forceinline__ f32x4 mfma16(bf16x8 a, bf16x8 b, f32x4 c) {
  return __builtin_amdgcn_mfma_f32_16x16x32_bf16(a, b, c, 0, 0, 0);
}
__device__ __forceinline__ unsigned short f2bf(float f) {
  unsigned u = __builtin_bit_cast(unsigned, f);
  u += 0x7FFFu + ((u >> 16) & 1u);
  return (unsigned short)(u >> 16);
}
__device__ __forceinline__ float bf2f(unsigned short h) {
  unsigned u = ((unsigned)h) << 16;
  return __builtin_bit_cast(float, u);
}

// ---------------- fp32 -> bf16 bulk convert (for Wh) ----------------
__global__ __launch_bounds__(256) void cvt4_kernel(const float* __restrict__ s,
                                                   unsigned short* __restrict__ d) {
  int i = (blockIdx.x * 256 + threadIdx.x) * 4;
  float4 v = *(const float4*)(s + i);
  ushort4 u = { f2bf(v.x), f2bf(v.y), f2bf(v.z), f2bf(v.w) };
  *(ushort4*)(d + i) = u;
}

// ---------------- GEMM: C[m][n] = sum_k A[m][k] * Bw[n][k] (+bias) ----------------
// MODE 0: A = x fp32 [32768][512], Bw = Wx_w fp32 [1024][512], bias1=Wx_b bias2=Wh_b
//         C = xp bf16 [T*B][H], row remap m=(b*1024+t) -> (t*32+b)
// MODE 1: A = h_hist bf16 [32768][1024], Bw = Wy_w fp32 [512][1024], bias1=Wy_b
//         C = out fp32 [B][T][Do], row remap m=(t*32+b) -> (b*1024+t)
template <int MODE>
__global__ __launch_bounds__(256)
void gemm_kernel(const void* __restrict__ Ap, const float* __restrict__ Bw,
                 const float* __restrict__ bias1, const float* __restrict__ bias2,
                 void* __restrict__ Cp) {
  constexpr int K = (MODE == 0) ? Di : Hh;
  constexpr int BM = 64, BN = 64, BK = 64;
  __shared__ unsigned short As[BM][80];
  __shared__ unsigned short Bs[BN][80];

  const int m0 = blockIdx.x * BM;
  const int n0 = blockIdx.y * BN;
  const int tid = threadIdx.x;
  const int lane = tid & 63;
  const int wave = tid >> 6;
  const int wm = (wave & 1) * 32;
  const int wn = (wave >> 1) * 32;
  const int fr = lane & 15;
  const int kg = lane >> 4;

  f32x4 acc[2][2] = {};

  const int srow = tid >> 2;          // 0..63
  const int scb  = (tid & 3) * 16;    // 0,16,32,48

  for (int k0 = 0; k0 < K; k0 += BK) {
    // stage A tile
    if constexpr (MODE == 0) {
      const float* a = (const float*)Ap + (size_t)(m0 + srow) * K + k0 + scb;
#pragma unroll
      for (int q = 0; q < 4; ++q) {
        float4 v = ((const float4*)a)[q];
        ushort4 u = { f2bf(v.x), f2bf(v.y), f2bf(v.z), f2bf(v.w) };
        *(ushort4*)&As[srow][scb + q * 4] = u;
      }
    } else {
      const unsigned short* a = (const unsigned short*)Ap + (size_t)(m0 + srow) * K + k0 + scb;
      *(uint4*)&As[srow][scb]     = ((const uint4*)a)[0];
      *(uint4*)&As[srow][scb + 8] = ((const uint4*)a)[1];
    }
    // stage B tile (always fp32 source)
    {
      const float* b = Bw + (size_t)(n0 + srow) * K + k0 + scb;
#pragma unroll
      for (int q = 0; q < 4; ++q) {
        float4 v = ((const float4*)b)[q];
        ushort4 u = { f2bf(v.x), f2bf(v.y), f2bf(v.z), f2bf(v.w) };
        *(ushort4*)&Bs[srow][scb + q * 4] = u;
      }
    }
    __syncthreads();

#pragma unroll
    for (int kk = 0; kk < 2; ++kk) {
      const int kb = kk * 32 + kg * 8;
      bf16x8 af[2], bf[2];
      af[0] = *(const bf16x8*)&As[wm + fr][kb];
      af[1] = *(const bf16x8*)&As[wm + 16 + fr][kb];
      bf[0] = *(const bf16x8*)&Bs[wn + fr][kb];
      bf[1] = *(const bf16x8*)&Bs[wn + 16 + fr][kb];
#pragma unroll
      for (int i = 0; i < 2; ++i)
#pragma unroll
        for (int j = 0; j < 2; ++j)
          acc[i][j] = mfma16(af[i], bf[j], acc[i][j]);
    }
    __syncthreads();
  }

  // epilogue
#pragma unroll
  for (int i = 0; i < 2; ++i) {
#pragma unroll
    for (int j = 0; j < 2; ++j) {
      const int n = n0 + wn + j * 16 + fr;
      float bv;
      if constexpr (MODE == 0) bv = bias1[n] + bias2[n];
      else                     bv = bias1[n];
#pragma unroll
      for (int q = 0; q < 4; ++q) {
        const int m = m0 + wm + i * 16 + kg * 4 + q;
        float v = acc[i][j][q] + bv;
        if constexpr (MODE == 0) {
          int bb = m >> 10, ttt = m & 1023;
          ((unsigned short*)Cp)[((size_t)ttt * Bb + bb) * Hh + n] = f2bf(v);
        } else {
          int bb = m & 31, ttt = m >> 5;
          ((float*)Cp)[((size_t)bb * Tt + ttt) * Do + n] = v;
        }
      }
    }
  }
}

// ---------------- sequential scan ----------------
// grid = 32 blocks x 256 threads. block = (g = blockIdx>>4 batch-group of 16,
// r = blockIdx&15 row-slice of 64 h-rows). Wave w owns 16 rows (one MFMA N-tile).
// Wh fragments register-resident (32 K-steps x bf16x8 = 128 VGPR).
__global__ __launch_bounds__(256, 1)
void scan_kernel(const unsigned short* __restrict__ Whb,  // bf16 [H][H]
                 const unsigned short* __restrict__ xp,   // bf16 [T][B][H]
                 unsigned short* __restrict__ hist,       // bf16 [T][B][H]
                 unsigned short* __restrict__ hbuf,       // bf16 [2][B][H]
                 unsigned* __restrict__ cnt) {            // [2] padded *32
  const int g = blockIdx.x >> 4;
  const int r = blockIdx.x & 15;
  const int wave = threadIdx.x >> 6;
  const int lane = threadIdx.x & 63;
  const int rowbase = r * 64 + wave * 16;
  const int nloc = lane & 15;
  const int kgrp = lane >> 4;
  const int hrow = rowbase + nloc;   // this lane's h output column / Wh row
  const int gb0 = g * 16;

  // preload Wh fragments into registers
  bf16x8 wf[32];
  const unsigned short* wb = Whb + (size_t)hrow * Hh + kgrp * 8;
#pragma unroll
  for (int kk = 0; kk < 32; ++kk)
    wf[kk] = *(const bf16x8*)(wb + kk * 32);

  const size_t aoff = (size_t)(gb0 + nloc) * Hh + kgrp * 8;
  unsigned* mycnt = cnt + g * 32;  // 128B apart

  for (int t = 0; t < Tt; ++t) {
    const int par = t & 1;
    const unsigned short* hsrc = hbuf + (size_t)par * Bb * Hh;
    f32x4 acc0 = {0.f, 0.f, 0.f, 0.f}, acc1 = {0.f, 0.f, 0.f, 0.f};
#pragma unroll
    for (int kk = 0; kk < 32; kk += 2) {
      bf16x8 a0 = *(const bf16x8*)(hsrc + aoff + kk * 32);
      bf16x8 a1 = *(const bf16x8*)(hsrc + aoff + kk * 32 + 32);
      acc0 = mfma16(a0, wf[kk], acc0);
      acc1 = mfma16(a1, wf[kk + 1], acc1);
    }
    f32x4 acc = acc0 + acc1;

    unsigned short* hdst = hbuf + (size_t)(par ^ 1) * Bb * Hh;
    const size_t xbase = (size_t)t * Bb * Hh;
#pragma unroll
    for (int i = 0; i < 4; ++i) {
      const int mb = gb0 + kgrp * 4 + i;            // global batch
      float pre = acc[i] + bf2f(xp[xbase + (size_t)mb * Hh + hrow]);
      float h = 1.0f / (1.0f + __expf(-pre));
      unsigned short hb = f2bf(h);
      hdst[(size_t)mb * Hh + hrow] = hb;
      hist[xbase + (size_t)mb * Hh + hrow] = hb;
    }

    // group barrier: monotonic counter, release on arrive, relaxed spin
    __syncthreads();
    if (threadIdx.x == 0) {
      __hip_atomic_fetch_add(mycnt, 1u, __ATOMIC_RELEASE, __HIP_MEMORY_SCOPE_AGENT);
      const unsigned target = 16u * (unsigned)(t + 1);
      while (__hip_atomic_load(mycnt, __ATOMIC_RELAXED, __HIP_MEMORY_SCOPE_AGENT) < target) {}
    }
    __syncthreads();
    __threadfence();  // acquire: invalidate stale h lines before next step's loads
  }
}

// ---------------- launch ----------------
extern "C" void kernel_launch(void* const* d_in, const int* in_sizes, int n_in,
                              void* d_out, int out_size, void* d_ws, size_t ws_size,
                              hipStream_t stream) {
  const float* x    = (const float*)d_in[0];
  const float* Wh_w = (const float*)d_in[1];
  const float* Wh_b = (const float*)d_in[2];
  const float* Wx_w = (const float*)d_in[3];
  const float* Wx_b = (const float*)d_in[4];
  const float* Wy_w = (const float*)d_in[5];
  const float* Wy_b = (const float*)d_in[6];

  char* ws = (char*)d_ws;
  constexpr size_t XP_OFF   = 0;                       // bf16 [T][B][H] = 64 MiB
  constexpr size_t HIST_OFF = XP_OFF   + (size_t)Tt * Bb * Hh * 2;  // 64 MiB
  constexpr size_t WH_OFF   = HIST_OFF + (size_t)Tt * Bb * Hh * 2;  // 2 MiB
  constexpr size_t HBUF_OFF = WH_OFF   + (size_t)Hh * Hh * 2;       // 128 KiB
  constexpr size_t CNT_OFF  = HBUF_OFF + (size_t)2 * Bb * Hh * 2;   // 256 B

  unsigned short* xp   = (unsigned short*)(ws + XP_OFF);
  unsigned short* hist = (unsigned short*)(ws + HIST_OFF);
  unsigned short* whb  = (unsigned short*)(ws + WH_OFF);
  unsigned short* hbuf = (unsigned short*)(ws + HBUF_OFF);
  unsigned*       cnt  = (unsigned*)(ws + CNT_OFF);

  // zero h ping-pong buffers and barrier counters (every call: graph replays)
  hipMemsetAsync(ws + HBUF_OFF, 0, (size_t)2 * Bb * Hh * 2 + 256, stream);

  // Wh fp32 -> bf16
  cvt4_kernel<<<dim3((Hh * Hh) / (256 * 4)), dim3(256), 0, stream>>>(Wh_w, whb);

  // xp = x @ Wx^T + Wx_b + Wh_b   (stored [T][B][H] bf16)
  gemm_kernel<0><<<dim3((Bb * Tt) / 64, Hh / 64), dim3(256), 0, stream>>>(
      (const void*)x, Wx_w, Wx_b, Wh_b, (void*)xp);

  // sequential scan (cooperative: guarantees all 32 blocks co-resident)
  {
    void* sargs[5] = { (void*)&whb, (void*)&xp, (void*)&hist, (void*)&hbuf, (void*)&cnt };
    hipLaunchCooperativeKernel((const void*)scan_kernel, dim3(32), dim3(256), sargs, 0, stream);
  }

  // out = hist @ Wy^T + Wy_b  (fp32 [B][T][Do])
  gemm_kernel<1><<<dim3((Bb * Tt) / 64, Do / 64), dim3(256), 0, stream>>>(
      (const void*)hist, Wy_w, Wy_b, nullptr, d_out);
}

// Round 2
// 7148.390 us; speedup vs baseline: 1.4594x; 1.4594x over previous
//
#include <hip/hip_runtime.h>

// Problem dims (fixed)
constexpr int Bb = 32;    // batch
constexpr int Tt = 1024;  // time steps
constexpr int Hh = 1024;  // hidden
constexpr int Di = 512;   // input dim
constexpr int Do = 512;   // output dim

using bf16x8 = __attribute__((ext_vector_type(8))) short;
using f32x4  = __attribute__((ext_vector_type(4))) float;

__device__ __forceinline__ f32x4 mfma16(bf16x8 a, bf16x8 b, f32x4 c) {
  return __builtin_amdgcn_mfma_f32_16x16x32_bf16(a, b, c, 0, 0, 0);
}
__device__ __forceinline__ unsigned short f2bf(float f) {
  unsigned u = __builtin_bit_cast(unsigned, f);
  u += 0x7FFFu + ((u >> 16) & 1u);
  return (unsigned short)(u >> 16);
}
__device__ __forceinline__ float bf2f(unsigned short h) {
  unsigned u = ((unsigned)h) << 16;
  return __builtin_bit_cast(float, u);
}

// ---- LLC-direct (bypass L1+L2) accesses: cross-XCD visible without fences ----
__device__ __forceinline__ void llc_store_u16(void* p, unsigned v) {
  asm volatile("global_store_short %0, %1, off sc0 sc1" :: "v"(p), "v"(v) : "memory");
}
__device__ __forceinline__ void llc_store_u32(void* p, unsigned v) {
  asm volatile("global_store_dword %0, %1, off sc0 sc1" :: "v"(p), "v"(v) : "memory");
}
__device__ __forceinline__ uint4 llc_load_flags(const void* p) {  // load + wait (spin path)
  uint4 r;
  asm volatile("global_load_dwordx4 %0, %1, off sc0 sc1\n\ts_waitcnt vmcnt(0)"
               : "=v"(r) : "v"(p) : "memory");
  return r;
}

// ---------------- fp32 -> bf16 bulk convert (for Wh) ----------------
__global__ __launch_bounds__(256) void cvt4_kernel(const float* __restrict__ s,
                                                   unsigned short* __restrict__ d) {
  int i = (blockIdx.x * 256 + threadIdx.x) * 4;
  float4 v = *(const float4*)(s + i);
  ushort4 u = { f2bf(v.x), f2bf(v.y), f2bf(v.z), f2bf(v.w) };
  *(ushort4*)(d + i) = u;
}

// ---------------- GEMM: C[m][n] = sum_k A[m][k] * Bw[n][k] (+bias) ----------------
template <int MODE>
__global__ __launch_bounds__(256)
void gemm_kernel(const void* __restrict__ Ap, const float* __restrict__ Bw,
                 const float* __restrict__ bias1, const float* __restrict__ bias2,
                 void* __restrict__ Cp) {
  constexpr int K = (MODE == 0) ? Di : Hh;
  constexpr int BM = 64, BN = 64, BK = 64;
  __shared__ unsigned short As[BM][80];
  __shared__ unsigned short Bs[BN][80];

  const int m0 = blockIdx.x * BM;
  const int n0 = blockIdx.y * BN;
  const int tid = threadIdx.x;
  const int lane = tid & 63;
  const int wave = tid >> 6;
  const int wm = (wave & 1) * 32;
  const int wn = (wave >> 1) * 32;
  const int fr = lane & 15;
  const int kg = lane >> 4;

  f32x4 acc[2][2] = {};

  const int srow = tid >> 2;          // 0..63
  const int scb  = (tid & 3) * 16;    // 0,16,32,48

  for (int k0 = 0; k0 < K; k0 += BK) {
    if constexpr (MODE == 0) {
      const float* a = (const float*)Ap + (size_t)(m0 + srow) * K + k0 + scb;
#pragma unroll
      for (int q = 0; q < 4; ++q) {
        float4 v = ((const float4*)a)[q];
        ushort4 u = { f2bf(v.x), f2bf(v.y), f2bf(v.z), f2bf(v.w) };
        *(ushort4*)&As[srow][scb + q * 4] = u;
      }
    } else {
      const unsigned short* a = (const unsigned short*)Ap + (size_t)(m0 + srow) * K + k0 + scb;
      *(uint4*)&As[srow][scb]     = ((const uint4*)a)[0];
      *(uint4*)&As[srow][scb + 8] = ((const uint4*)a)[1];
    }
    {
      const float* b = Bw + (size_t)(n0 + srow) * K + k0 + scb;
#pragma unroll
      for (int q = 0; q < 4; ++q) {
        float4 v = ((const float4*)b)[q];
        ushort4 u = { f2bf(v.x), f2bf(v.y), f2bf(v.z), f2bf(v.w) };
        *(ushort4*)&Bs[srow][scb + q * 4] = u;
      }
    }
    __syncthreads();

#pragma unroll
    for (int kk = 0; kk < 2; ++kk) {
      const int kb = kk * 32 + kg * 8;
      bf16x8 af[2], bf[2];
      af[0] = *(const bf16x8*)&As[wm + fr][kb];
      af[1] = *(const bf16x8*)&As[wm + 16 + fr][kb];
      bf[0] = *(const bf16x8*)&Bs[wn + fr][kb];
      bf[1] = *(const bf16x8*)&Bs[wn + 16 + fr][kb];
#pragma unroll
      for (int i = 0; i < 2; ++i)
#pragma unroll
        for (int j = 0; j < 2; ++j)
          acc[i][j] = mfma16(af[i], bf[j], acc[i][j]);
    }
    __syncthreads();
  }

#pragma unroll
  for (int i = 0; i < 2; ++i) {
#pragma unroll
    for (int j = 0; j < 2; ++j) {
      const int n = n0 + wn + j * 16 + fr;
      float bv;
      if constexpr (MODE == 0) bv = bias1[n] + bias2[n];
      else                     bv = bias1[n];
#pragma unroll
      for (int q = 0; q < 4; ++q) {
        const int m = m0 + wm + i * 16 + kg * 4 + q;
        float v = acc[i][j][q] + bv;
        if constexpr (MODE == 0) {
          int bb = m >> 10, ttt = m & 1023;
          ((unsigned short*)Cp)[((size_t)ttt * Bb + bb) * Hh + n] = f2bf(v);
        } else {
          int bb = m & 31, ttt = m >> 5;
          ((float*)Cp)[((size_t)bb * Tt + ttt) * Do + n] = v;
        }
      }
    }
  }
}

// ---------------- sequential scan ----------------
// grid = 16 blocks x 512 threads. g = blockIdx>>3 (batch-group of 16),
// r = blockIdx&7 (row-slice of 128 h-rows). 8 waves x 16 rows each.
// Wh fragments pinned in registers (128 VGPR/lane, asm-pinned vs remat).
// h exchanged through LLC via sc0 sc1 ops; per-block flag words, no cache fences.
__global__ __launch_bounds__(512)
void scan_kernel(const unsigned short* __restrict__ Whb,  // bf16 [H][H]
                 const unsigned short* __restrict__ xp,   // bf16 [T][B][H]
                 unsigned short* __restrict__ hist,       // bf16 [T][B][H]
                 unsigned short* __restrict__ hbuf,       // bf16 [2][B][H]
                 unsigned* __restrict__ flags) {          // [2][64] (256B apart)
  __shared__ unsigned short panel[16 * 1024];  // [16 batches][1024 K], XOR-swizzled

  const int tid = threadIdx.x;
  const int g = blockIdx.x >> 3;
  const int r = blockIdx.x & 7;
  const int wave = tid >> 6;
  const int lane = tid & 63;
  const int nloc = lane & 15;
  const int kgrp = lane >> 4;
  const int hrow = r * 128 + wave * 16 + nloc;   // this lane's h output row
  const int gb0 = g * 16;
  const int xmask = (nloc & 7) << 3;

  // preload Wh fragments into registers, pin against rematerialization
  bf16x8 wf[32];
  {
    const unsigned short* wb = Whb + (size_t)hrow * Hh + kgrp * 8;
#pragma unroll
    for (int kk = 0; kk < 32; ++kk) wf[kk] = *(const bf16x8*)(wb + kk * 32);
#pragma unroll
    for (int kk = 0; kk < 32; ++kk) asm volatile("" : "+v"(wf[kk]));
  }

  unsigned* gflags = flags + g * 64;
  const int sb  = tid >> 5;         // 0..15: batch staged by this thread
  const int sk0 = (tid & 31) * 32;  // K start of its 64B chunk

  for (int t = 0; t < Tt; ++t) {
    const int par = t & 1;
    const unsigned short* hsrc = hbuf + (size_t)par * Bb * Hh;
    unsigned short* hdst = hbuf + (size_t)(par ^ 1) * Bb * Hh;

    // xp prefetch (normal cached loads; L2 stays warm — no invalidates anymore)
    unsigned short xpv[4];
    const size_t xb = (size_t)t * Bb * Hh + hrow;
#pragma unroll
    for (int i = 0; i < 4; ++i) xpv[i] = xp[xb + (size_t)(gb0 + kgrp * 4 + i) * Hh];

    // wait until all 8 producer blocks of this group posted step t
    if (tid == 0) {
      for (;;) {
        uint4 f0 = llc_load_flags(gflags);
        uint4 f1 = llc_load_flags(gflags + 4);
        unsigned mn = f0.x;
        mn = mn < f0.y ? mn : f0.y;  mn = mn < f0.z ? mn : f0.z;  mn = mn < f0.w ? mn : f0.w;
        mn = mn < f1.x ? mn : f1.x;  mn = mn < f1.y ? mn : f1.y;
        mn = mn < f1.z ? mn : f1.z;  mn = mn < f1.w ? mn : f1.w;
        if (mn >= (unsigned)t) break;
      }
    }
    __syncthreads();

    // stage h panel [16 batches][1024] -> swizzled LDS (agent-scope loads bypass L1/L2)
    {
      const unsigned* gsrc = (const unsigned*)(hsrc + (size_t)(gb0 + sb) * Hh + sk0);
      unsigned tmp[16];
#pragma unroll
      for (int q = 0; q < 16; ++q)
        tmp[q] = __hip_atomic_load(gsrc + q, __ATOMIC_RELAXED, __HIP_MEMORY_SCOPE_AGENT);
#pragma unroll
      for (int c = 0; c < 4; ++c) {
        uint4 v = { tmp[4 * c], tmp[4 * c + 1], tmp[4 * c + 2], tmp[4 * c + 3] };
        *(uint4*)&panel[sb * 1024 + ((sk0 + c * 8) ^ ((sb & 7) << 3))] = v;
      }
    }
    __syncthreads();

    // MFMA: [16 batch] x [16 rows] over K=1024
    f32x4 acc0 = {0.f, 0.f, 0.f, 0.f}, acc1 = {0.f, 0.f, 0.f, 0.f};
#pragma unroll
    for (int kk = 0; kk < 32; kk += 2) {
      bf16x8 a0 = *(const bf16x8*)&panel[nloc * 1024 + ((kk * 32 + kgrp * 8) ^ xmask)];
      bf16x8 a1 = *(const bf16x8*)&panel[nloc * 1024 + (((kk + 1) * 32 + kgrp * 8) ^ xmask)];
      acc0 = mfma16(a0, wf[kk], acc0);
      acc1 = mfma16(a1, wf[kk + 1], acc1);
    }
    f32x4 acc = acc0 + acc1;

    // epilogue: sigmoid, publish h to LLC, record history (cached)
    const size_t tb = (size_t)t * Bb * Hh;
#pragma unroll
    for (int i = 0; i < 4; ++i) {
      const int mb = gb0 + kgrp * 4 + i;
      float pre = acc[i] + bf2f(xpv[i]);
      float h = 1.0f / (1.0f + __expf(-pre));
      unsigned hb = f2bf(h);
      llc_store_u16(hdst + (size_t)mb * Hh + hrow, hb);
      hist[tb + (size_t)mb * Hh + hrow] = (unsigned short)hb;
    }

    // drain stores (acked at LLC), block-wide barrier, post flag
    asm volatile("s_waitcnt vmcnt(0)" ::: "memory");
    __syncthreads();
    if (tid == 0) llc_store_u32(gflags + r, (unsigned)(t + 1));
  }
}

// ---------------- launch ----------------
extern "C" void kernel_launch(void* const* d_in, const int* in_sizes, int n_in,
                              void* d_out, int out_size, void* d_ws, size_t ws_size,
                              hipStream_t stream) {
  const float* x    = (const float*)d_in[0];
  const float* Wh_w = (const float*)d_in[1];
  const float* Wh_b = (const float*)d_in[2];
  const float* Wx_w = (const float*)d_in[3];
  const float* Wx_b = (const float*)d_in[4];
  const float* Wy_w = (const float*)d_in[5];
  const float* Wy_b = (const float*)d_in[6];

  char* ws = (char*)d_ws;
  constexpr size_t XP_OFF   = 0;                                     // bf16 [T][B][H] = 64 MiB
  constexpr size_t HIST_OFF = XP_OFF   + (size_t)Tt * Bb * Hh * 2;   // 64 MiB
  constexpr size_t WH_OFF   = HIST_OFF + (size_t)Tt * Bb * Hh * 2;   // 2 MiB
  constexpr size_t HBUF_OFF = WH_OFF   + (size_t)Hh * Hh * 2;        // 128 KiB
  constexpr size_t FLG_OFF  = HBUF_OFF + (size_t)2 * Bb * Hh * 2;    // 512 B

  unsigned short* xp   = (unsigned short*)(ws + XP_OFF);
  unsigned short* hist = (unsigned short*)(ws + HIST_OFF);
  unsigned short* whb  = (unsigned short*)(ws + WH_OFF);
  unsigned short* hbuf = (unsigned short*)(ws + HBUF_OFF);
  unsigned*       flags = (unsigned*)(ws + FLG_OFF);

  // zero h ping-pong buffers and flags (runs inside the graph each replay)
  hipMemsetAsync(ws + HBUF_OFF, 0, (size_t)2 * Bb * Hh * 2 + 512, stream);

  // Wh fp32 -> bf16
  cvt4_kernel<<<dim3((Hh * Hh) / (256 * 4)), dim3(256), 0, stream>>>(Wh_w, whb);

  // xp = x @ Wx^T + Wx_b + Wh_b   (stored [T][B][H] bf16)
  gemm_kernel<0><<<dim3((Bb * Tt) / 64, Hh / 64), dim3(256), 0, stream>>>(
      (const void*)x, Wx_w, Wx_b, Wh_b, (void*)xp);

  // sequential scan (cooperative: all 16 blocks co-resident)
  {
    void* sargs[5] = { (void*)&whb, (void*)&xp, (void*)&hist, (void*)&hbuf, (void*)&flags };
    hipLaunchCooperativeKernel((const void*)scan_kernel, dim3(16), dim3(512), sargs, 0, stream);
  }

  // out = hist @ Wy^T + Wy_b  (fp32 [B][T][Do])
  gemm_kernel<1><<<dim3((Bb * Tt) / 64, Do / 64), dim3(256), 0, stream>>>(
      (const void*)hist, Wy_w, Wy_b, nullptr, d_out);
}

// Round 4
// 5938.433 us; speedup vs baseline: 1.7567x; 1.2038x over previous
//
#include <hip/hip_runtime.h>

// Problem dims (fixed)
constexpr int Bb = 32;    // batch
constexpr int Tt = 1024;  // time steps
constexpr int Hh = 1024;  // hidden
constexpr int Di = 512;   // input dim
constexpr int Do = 512;   // output dim
constexpr int TGSZ = Bb * Hh;  // dwords per tagged h buffer slot

using bf16x8 = __attribute__((ext_vector_type(8))) short;
using f32x4  = __attribute__((ext_vector_type(4))) float;

__device__ __forceinline__ f32x4 mfma16(bf16x8 a, bf16x8 b, f32x4 c) {
  return __builtin_amdgcn_mfma_f32_16x16x32_bf16(a, b, c, 0, 0, 0);
}
__device__ __forceinline__ unsigned short f2bf(float f) {
  unsigned u = __builtin_bit_cast(unsigned, f);
  u += 0x7FFFu + ((u >> 16) & 1u);
  return (unsigned short)(u >> 16);
}
__device__ __forceinline__ float bf2f(unsigned short h) {
  unsigned u = ((unsigned)h) << 16;
  return __builtin_bit_cast(float, u);
}

// ---------------- fp32 -> bf16 bulk convert (for Wh) ----------------
__global__ __launch_bounds__(256) void cvt4_kernel(const float* __restrict__ s,
                                                   unsigned short* __restrict__ d) {
  int i = (blockIdx.x * 256 + threadIdx.x) * 4;
  float4 v = *(const float4*)(s + i);
  ushort4 u = { f2bf(v.x), f2bf(v.y), f2bf(v.z), f2bf(v.w) };
  *(ushort4*)(d + i) = u;
}

// ---------------- tagged-buffer init ----------------
// buf[0] = h_{-1}=0 with tag 0xFFFF (expected at t=0); buf[1],buf[2] = never-valid tag.
__global__ __launch_bounds__(256) void init_tags(unsigned* __restrict__ tg) {
  int i = blockIdx.x * 256 + threadIdx.x;
  tg[i] = (i < TGSZ) ? 0xFFFF0000u : 0xEEEE0000u;
}

// ---------------- GEMM: C[m][n] = sum_k A[m][k] * Bw[n][k] (+bias) ----------------
template <int MODE>
__global__ __launch_bounds__(256)
void gemm_kernel(const void* __restrict__ Ap, const float* __restrict__ Bw,
                 const float* __restrict__ bias1, const float* __restrict__ bias2,
                 void* __restrict__ Cp) {
  constexpr int K = (MODE == 0) ? Di : Hh;
  constexpr int BM = 64, BN = 64, BK = 64;
  __shared__ unsigned short As[BM][80];
  __shared__ unsigned short Bs[BN][80];

  const int m0 = blockIdx.x * BM;
  const int n0 = blockIdx.y * BN;
  const int tid = threadIdx.x;
  const int lane = tid & 63;
  const int wave = tid >> 6;
  const int wm = (wave & 1) * 32;
  const int wn = (wave >> 1) * 32;
  const int fr = lane & 15;
  const int kg = lane >> 4;

  f32x4 acc[2][2] = {};

  const int srow = tid >> 2;          // 0..63
  const int scb  = (tid & 3) * 16;    // 0,16,32,48

  for (int k0 = 0; k0 < K; k0 += BK) {
    if constexpr (MODE == 0) {
      const float* a = (const float*)Ap + (size_t)(m0 + srow) * K + k0 + scb;
#pragma unroll
      for (int q = 0; q < 4; ++q) {
        float4 v = ((const float4*)a)[q];
        ushort4 u = { f2bf(v.x), f2bf(v.y), f2bf(v.z), f2bf(v.w) };
        *(ushort4*)&As[srow][scb + q * 4] = u;
      }
    } else {
      const unsigned short* a = (const unsigned short*)Ap + (size_t)(m0 + srow) * K + k0 + scb;
      *(uint4*)&As[srow][scb]     = ((const uint4*)a)[0];
      *(uint4*)&As[srow][scb + 8] = ((const uint4*)a)[1];
    }
    {
      const float* b = Bw + (size_t)(n0 + srow) * K + k0 + scb;
#pragma unroll
      for (int q = 0; q < 4; ++q) {
        float4 v = ((const float4*)b)[q];
        ushort4 u = { f2bf(v.x), f2bf(v.y), f2bf(v.z), f2bf(v.w) };
        *(ushort4*)&Bs[srow][scb + q * 4] = u;
      }
    }
    __syncthreads();

#pragma unroll
    for (int kk = 0; kk < 2; ++kk) {
      const int kb = kk * 32 + kg * 8;
      bf16x8 af[2], bfr[2];
      af[0]  = *(const bf16x8*)&As[wm + fr][kb];
      af[1]  = *(const bf16x8*)&As[wm + 16 + fr][kb];
      bfr[0] = *(const bf16x8*)&Bs[wn + fr][kb];
      bfr[1] = *(const bf16x8*)&Bs[wn + 16 + fr][kb];
#pragma unroll
      for (int i = 0; i < 2; ++i)
#pragma unroll
        for (int j = 0; j < 2; ++j)
          acc[i][j] = mfma16(af[i], bfr[j], acc[i][j]);
    }
    __syncthreads();
  }

#pragma unroll
  for (int i = 0; i < 2; ++i) {
#pragma unroll
    for (int j = 0; j < 2; ++j) {
      const int n = n0 + wn + j * 16 + fr;
      float bv;
      if constexpr (MODE == 0) bv = bias1[n] + bias2[n];
      else                     bv = bias1[n];
#pragma unroll
      for (int q = 0; q < 4; ++q) {
        const int m = m0 + wm + i * 16 + kg * 4 + q;
        float v = acc[i][j][q] + bv;
        if constexpr (MODE == 0) {
          int bb = m >> 10, ttt = m & 1023;
          ((unsigned short*)Cp)[((size_t)ttt * Bb + bb) * Hh + n] = f2bf(v);
        } else {
          int bb = m & 31, ttt = m >> 5;
          ((float*)Cp)[((size_t)bb * Tt + ttt) * Do + n] = v;
        }
      }
    }
  }
}

// ---------------- sequential scan ----------------
// 16 blocks x 512 threads: g = blockIdx>>3 (batch-group of 16), r = blockIdx&7
// (128 h-rows). h exchanged as LLC-homed tagged dwords (tag<<16 | bf16), 3-buffer
// rotation; consumers poll their own chunk (detecting load IS the data load).
// No flags, no fences, no atomics. Wh register-resident (pinned in-loop).
__global__ __launch_bounds__(512)
void scan_kernel(const unsigned short* __restrict__ Whb,  // bf16 [H][H]
                 const unsigned short* __restrict__ xp,   // bf16 [T][B][H]
                 unsigned short* __restrict__ hist,       // bf16 [T][B][H]
                 unsigned* __restrict__ tg) {             // tagged [3][B][H]
  __shared__ unsigned short panel[16 * 1024];  // [16 batches][1024 K], XOR-swizzled

  const int tid = threadIdx.x;
  const int g = blockIdx.x >> 3;
  const int r = blockIdx.x & 7;
  const int wave = tid >> 6;
  const int lane = tid & 63;
  const int nloc = lane & 15;
  const int kgrp = lane >> 4;
  const int hrow = r * 128 + wave * 16 + nloc;   // this lane's h output row
  const int gb0 = g * 16;
  const int xmask = (nloc & 7) << 3;

  // preload Wh fragments into registers (pinned loop-carried below)
  bf16x8 wf[32];
  {
    const unsigned short* wb = Whb + (size_t)hrow * Hh + kgrp * 8;
#pragma unroll
    for (int kk = 0; kk < 32; ++kk) wf[kk] = *(const bf16x8*)(wb + kk * 32);
  }

  const int sb  = tid & 15;   // batch (within group) staged by this thread
  const int kc  = tid >> 4;   // 0..31: its 32-element K chunk
  const int sxs = (sb & 7) << 3;

  for (int t = 0; t < Tt; ++t) {
    // pin Wh fragments: force true register residency across iterations
#pragma unroll
    for (int kk = 0; kk < 32; kk += 8)
      asm volatile("" : "+v"(wf[kk]), "+v"(wf[kk + 1]), "+v"(wf[kk + 2]), "+v"(wf[kk + 3]),
                        "+v"(wf[kk + 4]), "+v"(wf[kk + 5]), "+v"(wf[kk + 6]), "+v"(wf[kk + 7]));

    const int par = t % 3;
    const int nxt = (t + 1) % 3;

    // xp prefetch (normal cached loads; overlaps the poll)
    unsigned short xpv[4];
    const size_t xb = (size_t)t * Bb * Hh + hrow;
#pragma unroll
    for (int i = 0; i < 4; ++i) xpv[i] = xp[xb + (size_t)(gb0 + kgrp * 4 + i) * Hh];

    // poll my 32-word chunk of h^{t-1} until every word carries tag t-1.
    // vmcnt(0) here also drains our previous-iteration stores (same counter).
    const unsigned exp = ((unsigned)t - 1u) & 0xFFFFu;
    const unsigned* src = tg + (size_t)par * TGSZ + (size_t)(gb0 + sb) * Hh + kc * 32;
    uint4 d0, d1, d2, d3, d4, d5, d6, d7;
    unsigned bad;
    do {
      asm volatile(
          "global_load_dwordx4 %0, %8, off sc0 sc1\n\t"
          "global_load_dwordx4 %1, %8, off offset:16 sc0 sc1\n\t"
          "global_load_dwordx4 %2, %8, off offset:32 sc0 sc1\n\t"
          "global_load_dwordx4 %3, %8, off offset:48 sc0 sc1\n\t"
          "global_load_dwordx4 %4, %8, off offset:64 sc0 sc1\n\t"
          "global_load_dwordx4 %5, %8, off offset:80 sc0 sc1\n\t"
          "global_load_dwordx4 %6, %8, off offset:96 sc0 sc1\n\t"
          "global_load_dwordx4 %7, %8, off offset:112 sc0 sc1\n\t"
          "s_waitcnt vmcnt(0)"
          : "=v"(d0), "=v"(d1), "=v"(d2), "=v"(d3),
            "=v"(d4), "=v"(d5), "=v"(d6), "=v"(d7)
          : "v"(src) : "memory");
      bad = 0;
#define CHK(v) bad |= ((v.x >> 16) ^ exp) | ((v.y >> 16) ^ exp) | \
                      ((v.z >> 16) ^ exp) | ((v.w >> 16) ^ exp)
      CHK(d0); CHK(d1); CHK(d2); CHK(d3); CHK(d4); CHK(d5); CHK(d6); CHK(d7);
#undef CHK
    } while (bad);

    // strip tags, pack to bf16 pairs, write swizzled LDS panel
    {
#define PK(a, b) (((a) & 0xFFFFu) | ((b) << 16))
      uint4 p0 = { PK(d0.x, d0.y), PK(d0.z, d0.w), PK(d1.x, d1.y), PK(d1.z, d1.w) };
      uint4 p1 = { PK(d2.x, d2.y), PK(d2.z, d2.w), PK(d3.x, d3.y), PK(d3.z, d3.w) };
      uint4 p2 = { PK(d4.x, d4.y), PK(d4.z, d4.w), PK(d5.x, d5.y), PK(d5.z, d5.w) };
      uint4 p3 = { PK(d6.x, d6.y), PK(d6.z, d6.w), PK(d7.x, d7.y), PK(d7.z, d7.w) };
#undef PK
      const int pb = sb * 1024, k0 = kc * 32;
      *(uint4*)&panel[pb + ((k0)      ^ sxs)] = p0;
      *(uint4*)&panel[pb + ((k0 + 8)  ^ sxs)] = p1;
      *(uint4*)&panel[pb + ((k0 + 16) ^ sxs)] = p2;
      *(uint4*)&panel[pb + ((k0 + 24) ^ sxs)] = p3;
    }
    __syncthreads();

    // MFMA: [16 batch] x [16 rows] over K=1024
    f32x4 acc0 = {0.f, 0.f, 0.f, 0.f}, acc1 = {0.f, 0.f, 0.f, 0.f};
#pragma unroll
    for (int kk = 0; kk < 32; kk += 2) {
      bf16x8 a0 = *(const bf16x8*)&panel[nloc * 1024 + ((kk * 32 + kgrp * 8) ^ xmask)];
      bf16x8 a1 = *(const bf16x8*)&panel[nloc * 1024 + (((kk + 1) * 32 + kgrp * 8) ^ xmask)];
      acc0 = mfma16(a0, wf[kk], acc0);
      acc1 = mfma16(a1, wf[kk + 1], acc1);
    }
    f32x4 acc = acc0 + acc1;

    // epilogue: sigmoid, publish tagged h^{t} into buf[(t+1)%3], record history
    const size_t tb = (size_t)t * Bb * Hh;
    unsigned* dbase = tg + (size_t)nxt * TGSZ + hrow;
#pragma unroll
    for (int i = 0; i < 4; ++i) {
      const int mb = gb0 + kgrp * 4 + i;
      float pre = acc[i] + bf2f(xpv[i]);
      float h = 1.0f / (1.0f + __expf(-pre));
      unsigned short hb = f2bf(h);
      unsigned word = ((unsigned)t << 16) | (unsigned)hb;
      asm volatile("global_store_dword %0, %1, off sc0 sc1"
                   :: "v"(dbase + (size_t)mb * Hh), "v"(word) : "memory");
      hist[tb + (size_t)mb * Hh + hrow] = hb;
    }

    // protect LDS panel from next iteration's staging until all waves read it
    __syncthreads();
  }
}

// ---------------- launch ----------------
extern "C" void kernel_launch(void* const* d_in, const int* in_sizes, int n_in,
                              void* d_out, int out_size, void* d_ws, size_t ws_size,
                              hipStream_t stream) {
  const float* x    = (const float*)d_in[0];
  const float* Wh_w = (const float*)d_in[1];
  const float* Wh_b = (const float*)d_in[2];
  const float* Wx_w = (const float*)d_in[3];
  const float* Wx_b = (const float*)d_in[4];
  const float* Wy_w = (const float*)d_in[5];
  const float* Wy_b = (const float*)d_in[6];

  char* ws = (char*)d_ws;
  constexpr size_t XP_OFF   = 0;                                     // bf16 [T][B][H] = 64 MiB
  constexpr size_t HIST_OFF = XP_OFF   + (size_t)Tt * Bb * Hh * 2;   // 64 MiB
  constexpr size_t WH_OFF   = HIST_OFF + (size_t)Tt * Bb * Hh * 2;   // 2 MiB
  constexpr size_t TG_OFF   = WH_OFF   + (size_t)Hh * Hh * 2;        // 384 KiB

  unsigned short* xp   = (unsigned short*)(ws + XP_OFF);
  unsigned short* hist = (unsigned short*)(ws + HIST_OFF);
  unsigned short* whb  = (unsigned short*)(ws + WH_OFF);
  unsigned*       tg   = (unsigned*)(ws + TG_OFF);

  // tagged-buffer init (fully rewrites all 3 slots every call — no memset needed)
  init_tags<<<dim3((3 * TGSZ) / 256), dim3(256), 0, stream>>>(tg);

  // Wh fp32 -> bf16
  cvt4_kernel<<<dim3((Hh * Hh) / (256 * 4)), dim3(256), 0, stream>>>(Wh_w, whb);

  // xp = x @ Wx^T + Wx_b + Wh_b   (stored [T][B][H] bf16)
  gemm_kernel<0><<<dim3((Bb * Tt) / 64, Hh / 64), dim3(256), 0, stream>>>(
      (const void*)x, Wx_w, Wx_b, Wh_b, (void*)xp);

  // sequential scan (cooperative: all 16 blocks co-resident)
  {
    void* sargs[4] = { (void*)&whb, (void*)&xp, (void*)&hist, (void*)&tg };
    hipLaunchCooperativeKernel((const void*)scan_kernel, dim3(16), dim3(512), sargs, 0, stream);
  }

  // out = hist @ Wy^T + Wy_b  (fp32 [B][T][Do])
  gemm_kernel<1><<<dim3((Bb * Tt) / 64, Do / 64), dim3(256), 0, stream>>>(
      (const void*)hist, Wy_w, Wy_b, nullptr, d_out);
}

// Round 10
// 5853.258 us; speedup vs baseline: 1.7823x; 1.0146x over previous
//
#include <hip/hip_runtime.h>

// Problem dims (fixed)
constexpr int Bb = 32;    // batch
constexpr int Tt = 1024;  // time steps
constexpr int Hh = 1024;  // hidden
constexpr int Di = 512;   // input dim
constexpr int Do = 512;   // output dim
constexpr int TGSZ = Bb * Hh;  // dwords per tagged h buffer slot

using bf16x8 = __attribute__((ext_vector_type(8))) short;
using f32x4  = __attribute__((ext_vector_type(4))) float;

__device__ __forceinline__ f32x4 mfma16(bf16x8 a, bf16x8 b, f32x4 c) {
  return __builtin_amdgcn_mfma_f32_16x16x32_bf16(a, b, c, 0, 0, 0);
}
__device__ __forceinline__ unsigned short f2bf(float f) {
  unsigned u = __builtin_bit_cast(unsigned, f);
  u += 0x7FFFu + ((u >> 16) & 1u);
  return (unsigned short)(u >> 16);
}
__device__ __forceinline__ float bf2f(unsigned short h) {
  unsigned u = ((unsigned)h) << 16;
  return __builtin_bit_cast(float, u);
}

// ---------------- fp32 -> bf16 bulk convert (for Wh) ----------------
__global__ __launch_bounds__(256) void cvt4_kernel(const float* __restrict__ s,
                                                   unsigned short* __restrict__ d) {
  int i = (blockIdx.x * 256 + threadIdx.x) * 4;
  float4 v = *(const float4*)(s + i);
  ushort4 u = { f2bf(v.x), f2bf(v.y), f2bf(v.z), f2bf(v.w) };
  *(ushort4*)(d + i) = u;
}

// ---------------- tagged-buffer init ----------------
// buf[0] = h_{-1}=0 with tag 0xFFFF (expected at t=0); buf[1],buf[2] = never-valid tag.
__global__ __launch_bounds__(256) void init_tags(unsigned* __restrict__ tg) {
  int i = blockIdx.x * 256 + threadIdx.x;
  tg[i] = (i < TGSZ) ? 0xFFFF0000u : 0xEEEE0000u;
}

// ---------------- GEMM: C[m][n] = sum_k A[m][k] * Bw[n][k] (+bias) ----------------
template <int MODE>
__global__ __launch_bounds__(256)
void gemm_kernel(const void* __restrict__ Ap, const float* __restrict__ Bw,
                 const float* __restrict__ bias1, const float* __restrict__ bias2,
                 void* __restrict__ Cp) {
  constexpr int K = (MODE == 0) ? Di : Hh;
  constexpr int BM = 64, BN = 64, BK = 64;
  __shared__ unsigned short As[BM][80];
  __shared__ unsigned short Bs[BN][80];

  const int m0 = blockIdx.x * BM;
  const int n0 = blockIdx.y * BN;
  const int tid = threadIdx.x;
  const int lane = tid & 63;
  const int wave = tid >> 6;
  const int wm = (wave & 1) * 32;
  const int wn = (wave >> 1) * 32;
  const int fr = lane & 15;
  const int kg = lane >> 4;

  f32x4 acc[2][2] = {};

  const int srow = tid >> 2;          // 0..63
  const int scb  = (tid & 3) * 16;    // 0,16,32,48

  for (int k0 = 0; k0 < K; k0 += BK) {
    if constexpr (MODE == 0) {
      const float* a = (const float*)Ap + (size_t)(m0 + srow) * K + k0 + scb;
#pragma unroll
      for (int q = 0; q < 4; ++q) {
        float4 v = ((const float4*)a)[q];
        ushort4 u = { f2bf(v.x), f2bf(v.y), f2bf(v.z), f2bf(v.w) };
        *(ushort4*)&As[srow][scb + q * 4] = u;
      }
    } else {
      const unsigned short* a = (const unsigned short*)Ap + (size_t)(m0 + srow) * K + k0 + scb;
      *(uint4*)&As[srow][scb]     = ((const uint4*)a)[0];
      *(uint4*)&As[srow][scb + 8] = ((const uint4*)a)[1];
    }
    {
      const float* b = Bw + (size_t)(n0 + srow) * K + k0 + scb;
#pragma unroll
      for (int q = 0; q < 4; ++q) {
        float4 v = ((const float4*)b)[q];
        ushort4 u = { f2bf(v.x), f2bf(v.y), f2bf(v.z), f2bf(v.w) };
        *(ushort4*)&Bs[srow][scb + q * 4] = u;
      }
    }
    __syncthreads();

#pragma unroll
    for (int kk = 0; kk < 2; ++kk) {
      const int kb = kk * 32 + kg * 8;
      bf16x8 af[2], bfr[2];
      af[0]  = *(const bf16x8*)&As[wm + fr][kb];
      af[1]  = *(const bf16x8*)&As[wm + 16 + fr][kb];
      bfr[0] = *(const bf16x8*)&Bs[wn + fr][kb];
      bfr[1] = *(const bf16x8*)&Bs[wn + 16 + fr][kb];
#pragma unroll
      for (int i = 0; i < 2; ++i)
#pragma unroll
        for (int j = 0; j < 2; ++j)
          acc[i][j] = mfma16(af[i], bfr[j], acc[i][j]);
    }
    __syncthreads();
  }

#pragma unroll
  for (int i = 0; i < 2; ++i) {
#pragma unroll
    for (int j = 0; j < 2; ++j) {
      const int n = n0 + wn + j * 16 + fr;
      float bv;
      if constexpr (MODE == 0) bv = bias1[n] + bias2[n];
      else                     bv = bias1[n];
#pragma unroll
      for (int q = 0; q < 4; ++q) {
        const int m = m0 + wm + i * 16 + kg * 4 + q;
        float v = acc[i][j][q] + bv;
        if constexpr (MODE == 0) {
          int bb = m >> 10, ttt = m & 1023;
          ((unsigned short*)Cp)[((size_t)ttt * Bb + bb) * Hh + n] = f2bf(v);
        } else {
          int bb = m & 31, ttt = m >> 5;
          ((float*)Cp)[((size_t)bb * Tt + ttt) * Do + n] = v;
        }
      }
    }
  }
}

// ---------------- sequential scan ----------------
// 16 blocks x 512 threads: g = blockIdx>>3 (batch-group of 16), r = blockIdx&7
// (128 h-rows). h exchanged as LLC-homed tagged dwords (tag<<16 | bf16), 3-buffer
// rotation; the detecting load IS the data load. No flags, no fences, no atomics.
// Wh loaded via OPAQUE volatile-asm loads (non-rematerializable -> resident).
// ALL asm load outputs are EARLY-CLOBBER ("=&v"): without it the allocator may
// overlap the async-load dests with the address pair -> corrupted address ->
// GPU memory fault (R9's crash). Waitcnt lives INSIDE each load block.
// SAFETY: every spin is BOUNDED (8192 tries) -> wrong data on timeout, never a hang.
__global__ __launch_bounds__(512, 2)
void scan_kernel(const unsigned short* __restrict__ Whb,  // bf16 [H][H]
                 const unsigned short* __restrict__ xp,   // bf16 [T][B][H]
                 unsigned short* __restrict__ hist,       // bf16 [T][B][H]
                 unsigned* __restrict__ tg) {             // tagged [3][B][H]
  __shared__ unsigned short panel[16 * 1024];  // [16 batches][1024 K], XOR-swizzled

  const int tid = threadIdx.x;
  const int g = blockIdx.x >> 3;
  const int r = blockIdx.x & 7;
  const int wave = tid >> 6;
  const int lane = tid & 63;
  const int nloc = lane & 15;
  const int kgrp = lane >> 4;
  const int hrow = r * 128 + wave * 16 + nloc;   // this lane's h output row
  const int gb0 = g * 16;
  const int xmask = (nloc & 7) << 3;

  // preload Wh fragments via opaque asm loads (non-rematerializable roots).
  // wf[kk] = Whb[hrow][kgrp*8 + kk*32 .. +8)  (kk*64 bytes from base).
  // Early-clobber outputs + in-block waitcnt: dests disjoint from address pair,
  // values architecturally valid when each block retires.
  bf16x8 wf[32];
  {
    const unsigned short* wb = Whb + (size_t)hrow * Hh + kgrp * 8;
#pragma unroll
    for (int kk = 0; kk < 32; kk += 8) {
      const unsigned short* p = wb + kk * 32;  // 8 frags, 64B apart
      asm volatile(
          "global_load_dwordx4 %0, %8, off\n\t"
          "global_load_dwordx4 %1, %8, off offset:64\n\t"
          "global_load_dwordx4 %2, %8, off offset:128\n\t"
          "global_load_dwordx4 %3, %8, off offset:192\n\t"
          "global_load_dwordx4 %4, %8, off offset:256\n\t"
          "global_load_dwordx4 %5, %8, off offset:320\n\t"
          "global_load_dwordx4 %6, %8, off offset:384\n\t"
          "global_load_dwordx4 %7, %8, off offset:448\n\t"
          "s_waitcnt vmcnt(0)"
          : "=&v"(wf[kk + 0]), "=&v"(wf[kk + 1]), "=&v"(wf[kk + 2]), "=&v"(wf[kk + 3]),
            "=&v"(wf[kk + 4]), "=&v"(wf[kk + 5]), "=&v"(wf[kk + 6]), "=&v"(wf[kk + 7])
          : "v"(p)
          : "memory");
    }
  }

  const int sb  = tid & 15;   // batch (within group) staged by this thread
  const int kc  = tid >> 4;   // 0..31: its 32-element K chunk
  const int sxs = (sb & 7) << 3;

  for (int t = 0; t < Tt; ++t) {
    const int par = t % 3;
    const int nxt = (t + 1) % 3;

    // xp prefetch (normal cached loads; overlaps the poll)
    unsigned short xpv[4];
    const size_t xb = (size_t)t * Bb * Hh + hrow;
#pragma unroll
    for (int i = 0; i < 4; ++i) xpv[i] = xp[xb + (size_t)(gb0 + kgrp * 4 + i) * Hh];

    // poll my 32-word chunk of h^{t-1} until every word carries tag t-1.
    // BOUNDED: give up after 8192 rounds -> wrong data, never a hang.
    const unsigned exp = ((unsigned)t - 1u) & 0xFFFFu;
    const unsigned* src = tg + (size_t)par * TGSZ + (size_t)(gb0 + sb) * Hh + kc * 32;
    uint4 d0, d1, d2, d3, d4, d5, d6, d7;
    unsigned bad;
    int tries = 8192;
    do {
      asm volatile(
          "global_load_dwordx4 %0, %8, off sc0 sc1\n\t"
          "global_load_dwordx4 %1, %8, off offset:16 sc0 sc1\n\t"
          "global_load_dwordx4 %2, %8, off offset:32 sc0 sc1\n\t"
          "global_load_dwordx4 %3, %8, off offset:48 sc0 sc1\n\t"
          "global_load_dwordx4 %4, %8, off offset:64 sc0 sc1\n\t"
          "global_load_dwordx4 %5, %8, off offset:80 sc0 sc1\n\t"
          "global_load_dwordx4 %6, %8, off offset:96 sc0 sc1\n\t"
          "global_load_dwordx4 %7, %8, off offset:112 sc0 sc1\n\t"
          "s_waitcnt vmcnt(0)"
          : "=&v"(d0), "=&v"(d1), "=&v"(d2), "=&v"(d3),
            "=&v"(d4), "=&v"(d5), "=&v"(d6), "=&v"(d7)
          : "v"(src) : "memory");
      bad = 0;
#define CHK(v) bad |= ((v.x >> 16) ^ exp) | ((v.y >> 16) ^ exp) | \
                      ((v.z >> 16) ^ exp) | ((v.w >> 16) ^ exp)
      CHK(d0); CHK(d1); CHK(d2); CHK(d3); CHK(d4); CHK(d5); CHK(d6); CHK(d7);
#undef CHK
    } while (bad && --tries);

    // strip tags, pack to bf16 pairs, write swizzled LDS panel
    {
#define PK(a, b) (((a) & 0xFFFFu) | ((b) << 16))
      uint4 p0 = { PK(d0.x, d0.y), PK(d0.z, d0.w), PK(d1.x, d1.y), PK(d1.z, d1.w) };
      uint4 p1 = { PK(d2.x, d2.y), PK(d2.z, d2.w), PK(d3.x, d3.y), PK(d3.z, d3.w) };
      uint4 p2 = { PK(d4.x, d4.y), PK(d4.z, d4.w), PK(d5.x, d5.y), PK(d5.z, d5.w) };
      uint4 p3 = { PK(d6.x, d6.y), PK(d6.z, d6.w), PK(d7.x, d7.y), PK(d7.z, d7.w) };
#undef PK
      const int pb = sb * 1024, k0 = kc * 32;
      *(uint4*)&panel[pb + ((k0)      ^ sxs)] = p0;
      *(uint4*)&panel[pb + ((k0 + 8)  ^ sxs)] = p1;
      *(uint4*)&panel[pb + ((k0 + 16) ^ sxs)] = p2;
      *(uint4*)&panel[pb + ((k0 + 24) ^ sxs)] = p3;
    }
    __syncthreads();

    // MFMA: [16 batch] x [16 rows] over K=1024 (wf held resident by opaque defs)
    f32x4 acc0 = {0.f, 0.f, 0.f, 0.f}, acc1 = {0.f, 0.f, 0.f, 0.f};
#pragma unroll
    for (int kk = 0; kk < 32; kk += 2) {
      bf16x8 a0 = *(const bf16x8*)&panel[nloc * 1024 + ((kk * 32 + kgrp * 8) ^ xmask)];
      bf16x8 a1 = *(const bf16x8*)&panel[nloc * 1024 + (((kk + 1) * 32 + kgrp * 8) ^ xmask)];
      acc0 = mfma16(a0, wf[kk], acc0);
      acc1 = mfma16(a1, wf[kk + 1], acc1);
    }
    f32x4 acc = acc0 + acc1;

    // epilogue: sigmoid, publish tagged h^{t} into buf[(t+1)%3], record history
    const size_t tb = (size_t)t * Bb * Hh;
    unsigned* dbase = tg + (size_t)nxt * TGSZ + hrow;
#pragma unroll
    for (int i = 0; i < 4; ++i) {
      const int mb = gb0 + kgrp * 4 + i;
      float pre = acc[i] + bf2f(xpv[i]);
      float h = 1.0f / (1.0f + __expf(-pre));
      unsigned short hb = f2bf(h);
      unsigned word = ((unsigned)t << 16) | (unsigned)hb;
      asm volatile("global_store_dword %0, %1, off sc0 sc1"
                   :: "v"(dbase + (size_t)mb * Hh), "v"(word) : "memory");
      hist[tb + (size_t)mb * Hh + hrow] = hb;
    }

    // protect LDS panel from next iteration's staging until all waves read it
    __syncthreads();
  }
}

// ---------------- launch ----------------
extern "C" void kernel_launch(void* const* d_in, const int* in_sizes, int n_in,
                              void* d_out, int out_size, void* d_ws, size_t ws_size,
                              hipStream_t stream) {
  const float* x    = (const float*)d_in[0];
  const float* Wh_w = (const float*)d_in[1];
  const float* Wh_b = (const float*)d_in[2];
  const float* Wx_w = (const float*)d_in[3];
  const float* Wx_b = (const float*)d_in[4];
  const float* Wy_w = (const float*)d_in[5];
  const float* Wy_b = (const float*)d_in[6];

  char* ws = (char*)d_ws;
  constexpr size_t XP_OFF   = 0;                                     // bf16 [T][B][H] = 64 MiB
  constexpr size_t HIST_OFF = XP_OFF   + (size_t)Tt * Bb * Hh * 2;   // 64 MiB
  constexpr size_t WH_OFF   = HIST_OFF + (size_t)Tt * Bb * Hh * 2;   // 2 MiB
  constexpr size_t TG_OFF   = WH_OFF   + (size_t)Hh * Hh * 2;        // 384 KiB

  unsigned short* xp   = (unsigned short*)(ws + XP_OFF);
  unsigned short* hist = (unsigned short*)(ws + HIST_OFF);
  unsigned short* whb  = (unsigned short*)(ws + WH_OFF);
  unsigned*       tg   = (unsigned*)(ws + TG_OFF);

  // tagged-buffer init (fully rewrites all 3 slots every call — no memset needed)
  init_tags<<<dim3((3 * TGSZ) / 256), dim3(256), 0, stream>>>(tg);

  // Wh fp32 -> bf16
  cvt4_kernel<<<dim3((Hh * Hh) / (256 * 4)), dim3(256), 0, stream>>>(Wh_w, whb);

  // xp = x @ Wx^T + Wx_b + Wh_b   (stored [T][B][H] bf16)
  gemm_kernel<0><<<dim3((Bb * Tt) / 64, Hh / 64), dim3(256), 0, stream>>>(
      (const void*)x, Wx_w, Wx_b, Wh_b, (void*)xp);

  // sequential scan (cooperative: all 16 blocks co-resident)
  {
    void* sargs[4] = { (void*)&whb, (void*)&xp, (void*)&hist, (void*)&tg };
    hipLaunchCooperativeKernel((const void*)scan_kernel, dim3(16), dim3(512), sargs, 0, stream);
  }

  // out = hist @ Wy^T + Wy_b  (fp32 [B][T][Do])
  gemm_kernel<1><<<dim3((Bb * Tt) / 64, Do / 64), dim3(256), 0, stream>>>(
      (const void*)hist, Wy_w, Wy_b, nullptr, d_out);
}